// Round 3
// baseline (103.493 us; speedup 1.0000x reference)
//
#include <hip/hip_runtime.h>
#include <math.h>

#define NFEAT 768
#define NT    128

struct C { float r, i; };

// GF2-linear LDS swizzle (bijective; verified rank-4 bank spread for all patterns)
__device__ __forceinline__ int swz(int j){ return j ^ (j >> 4) ^ ((j >> 2) & 0xC); }

// Composite of the CNOT ring CNOT(0,1),...,CNOT(9,0): s_after[j] = s_before[perm(j)].
// XOR-linear: perm(a^b) = perm(a)^perm(b).
__device__ __forceinline__ int cnot_perm(int j){
  int i = j;
  i ^= ((i >> 0) & 1) << 9;
  i ^= ((i >> 1) & 1) << 0;
  i ^= ((i >> 2) & 1) << 1;
  i ^= ((i >> 3) & 1) << 2;
  i ^= ((i >> 4) & 1) << 3;
  i ^= ((i >> 5) & 1) << 4;
  i ^= ((i >> 6) & 1) << 5;
  i ^= ((i >> 7) & 1) << 6;
  i ^= ((i >> 8) & 1) << 7;
  i ^= ((i >> 9) & 1) << 8;
  return i;
}

__device__ __forceinline__ void applyU(const float4 A, const float4 B, C& a, C& b){
  const float ar=a.r, ai=a.i, br=b.r, bi=b.i;
  a.r = A.x*ar - A.y*ai + A.z*br - A.w*bi;
  a.i = A.x*ai + A.y*ar + A.z*bi + A.w*br;
  b.r = B.x*ar - B.y*ai + B.z*br - B.w*bi;
  b.i = B.x*ai + B.y*ar + B.z*bi + B.w*br;
}

__device__ __forceinline__ void applyRY(float c, float s, C& a, C& b){
  const float ar=a.r, ai=a.i, br=b.r, bi=b.i;
  a.r = c*ar - s*br; a.i = c*ai - s*bi;
  b.r = s*ar + c*br; b.i = s*ai + c*bi;
}

// DIF butterfly, positive exponent: a' = a+b ; b' = (a-b)*tw
__device__ __forceinline__ void bfly(C& a, C& b, const C tw){
  const C u = {a.r + b.r, a.i + b.i};
  const C v = {a.r - b.r, a.i - b.i};
  a = u;
  b.r = v.r*tw.r - v.i*tw.i;
  b.i = v.r*tw.i + v.i*tw.r;
}

template<int S>
__device__ __forceinline__ int baseS(int t){ return (t & ((1<<S)-1)) | ((t >> S) << (S+3)); }

template<int S>
__device__ __forceinline__ void rd8(const float2* buf, int a0, C* xv){
  #pragma unroll
  for (int m = 0; m < 8; ++m){
    const float2 r = buf[a0 ^ swz(m << S)];
    xv[m].r = r.x; xv[m].i = r.y;
  }
}
template<int S>
__device__ __forceinline__ void wr8(float2* buf, int a0, const C* xv){
  #pragma unroll
  for (int m = 0; m < 8; ++m)
    buf[a0 ^ swz(m << S)] = make_float2(xv[m].r, xv[m].i);
}

// three single-qubit gates on bits (P,P-1,P-2) <-> (m+4, m+2, m+1) pairs
__device__ __forceinline__ void apply3U(C* xv, const float4* g4, int Q){
  const float4 A0=g4[2*Q+0], B0=g4[2*Q+1];
  const float4 A1=g4[2*Q+2], B1=g4[2*Q+3];
  const float4 A2=g4[2*Q+4], B2=g4[2*Q+5];
  applyU(A0,B0,xv[0],xv[4]); applyU(A0,B0,xv[1],xv[5]); applyU(A0,B0,xv[2],xv[6]); applyU(A0,B0,xv[3],xv[7]);
  applyU(A1,B1,xv[0],xv[2]); applyU(A1,B1,xv[1],xv[3]); applyU(A1,B1,xv[4],xv[6]); applyU(A1,B1,xv[5],xv[7]);
  applyU(A2,B2,xv[0],xv[1]); applyU(A2,B2,xv[2],xv[3]); applyU(A2,B2,xv[4],xv[5]); applyU(A2,B2,xv[6],xv[7]);
}

__device__ __forceinline__ void apply3RY(C* xv, const float* gr, int Q){
  const float c0 = gr[2*Q+0], s0 = gr[2*Q+1];
  const float c1 = gr[2*Q+2], s1 = gr[2*Q+3];
  const float c2 = gr[2*Q+4], s2 = gr[2*Q+5];
  applyRY(c0,s0,xv[0],xv[4]); applyRY(c0,s0,xv[1],xv[5]); applyRY(c0,s0,xv[2],xv[6]); applyRY(c0,s0,xv[3],xv[7]);
  applyRY(c1,s1,xv[0],xv[2]); applyRY(c1,s1,xv[1],xv[3]); applyRY(c1,s1,xv[4],xv[6]); applyRY(c1,s1,xv[5],xv[7]);
  applyRY(c2,s2,xv[0],xv[1]); applyRY(c2,s2,xv[2],xv[3]); applyRY(c2,s2,xv[4],xv[5]); applyRY(c2,s2,xv[6],xv[7]);
}

// 3 DIF radix-2 stages on 8 regs; stage1 tw = tA*W(128m), stage2 tB*i^(m&1), stage3 tC
__device__ __forceinline__ void fft8_stages(C* xv, const C tA, const C tAE, const C tB, const C tC){
  const C itA  = {-tA.i,  tA.r};
  const C itAE = {-tAE.i, tAE.r};
  bfly(xv[0], xv[4], tA);  bfly(xv[1], xv[5], tAE);
  bfly(xv[2], xv[6], itA); bfly(xv[3], xv[7], itAE);
  const C itB = {-tB.i, tB.r};
  bfly(xv[0], xv[2], tB);  bfly(xv[1], xv[3], itB);
  bfly(xv[4], xv[6], tB);  bfly(xv[5], xv[7], itB);
  bfly(xv[0], xv[1], tC);  bfly(xv[2], xv[3], tC);
  bfly(xv[4], xv[5], tC);  bfly(xv[6], xv[7], tC);
}

template<int MASK>
__device__ __forceinline__ void pairsum(const C* z, float& xr, float& xi){
  float r = 0.f, ii = 0.f;
  #pragma unroll
  for (int m = 0; m < 8; ++m){
    if ((m & MASK) == 0){
      const C a = z[m], b = z[m | MASK];
      r  += a.r*b.r + a.i*b.i;
      ii += a.r*b.i - a.i*b.r;
    }
  }
  xr = r; xi = ii;
}

__global__ void gate_prep(const float* __restrict__ w, float* __restrict__ gt){
  const int t = threadIdx.x;
  if (t >= 10) return;
  const float ha = 0.5f*w[t*4+0], hb = 0.5f*w[t*4+1];
  const float hg = 0.5f*w[t*4+2], hd = 0.5f*w[t*4+3];
  const float ca = cosf(ha), sa = sinf(ha);
  const float cb = cosf(hb), sb = sinf(hb);
  const float cg = cosf(hg), sg = sinf(hg);
  C rx00={ca,0.f}, rx01={0.f,-sa}, rx10={0.f,-sa}, rx11={ca,0.f};
  C ry00={cb,0.f}, ry01={-sb,0.f}, ry10={sb,0.f},  ry11={cb,0.f};
  C a00 = { ry00.r*rx00.r - ry00.i*rx00.i + ry01.r*rx10.r - ry01.i*rx10.i,
            ry00.r*rx00.i + ry00.i*rx00.r + ry01.r*rx10.i + ry01.i*rx10.r };
  C a01 = { ry00.r*rx01.r - ry00.i*rx01.i + ry01.r*rx11.r - ry01.i*rx11.i,
            ry00.r*rx01.i + ry00.i*rx01.r + ry01.r*rx11.i + ry01.i*rx11.r };
  C a10 = { ry10.r*rx00.r - ry10.i*rx00.i + ry11.r*rx10.r - ry11.i*rx10.i,
            ry10.r*rx00.i + ry10.i*rx00.r + ry11.r*rx10.i + ry11.i*rx10.r };
  C a11 = { ry10.r*rx01.r - ry10.i*rx01.i + ry11.r*rx11.r - ry11.i*rx11.i,
            ry10.r*rx01.i + ry10.i*rx01.r + ry11.r*rx11.i + ry11.i*rx11.r };
  // RZ = diag(cg - i sg, cg + i sg)
  C u00 = { cg*a00.r + sg*a00.i, cg*a00.i - sg*a00.r };
  C u01 = { cg*a01.r + sg*a01.i, cg*a01.i - sg*a01.r };
  C u10 = { cg*a10.r - sg*a10.i, cg*a10.i + sg*a10.r };
  C u11 = { cg*a11.r - sg*a11.i, cg*a11.i + sg*a11.r };
  gt[8*t+0]=u00.r; gt[8*t+1]=u00.i; gt[8*t+2]=u01.r; gt[8*t+3]=u01.i;
  gt[8*t+4]=u10.r; gt[8*t+5]=u10.i; gt[8*t+6]=u11.r; gt[8*t+7]=u11.i;
  gt[80+2*t] = cosf(hd); gt[81+2*t] = sinf(hd);
}

__global__ void __launch_bounds__(NT, 8)
qqk_kernel(const float* __restrict__ x, const float* __restrict__ gt,
           float* __restrict__ out)
{
  __shared__ float2 buf[1024];   // swizzled state; later aliased as 12x33 float2 rows
  __shared__ float  wred[2];
  __shared__ float  wz[2][7];    // per-wave WH partials (total, d0..d5)

  const int b    = blockIdx.x;
  const int t    = threadIdx.x;
  const int wave = t >> 6;
  const int lane = t & 63;
  const float4* g4 = (const float4*)gt;
  const float*  gr = gt + 80;
  const int st = swz(t);

  // ---- global load (6 cols + 2 zero pads) + norm ----
  C xv[8];
  const float* xb = x + (size_t)b * NFEAT;
  float ss = 0.f;
  #pragma unroll
  for (int m = 0; m < 6; ++m){ const float v = xb[t + 128*m]; xv[m] = {v, 0.f}; ss += v*v; }
  xv[6] = {0.f,0.f}; xv[7] = {0.f,0.f};
  #pragma unroll
  for (int m = 1; m < 64; m <<= 1) ss += __shfl_xor(ss, m);
  if (lane == 0) wred[wave] = ss;
  __syncthreads();
  const float invn = 1.0f / fmaxf(sqrtf(wred[0] + wred[1]), 1e-8f);
  #pragma unroll
  for (int m = 0; m < 6; ++m) xv[m].r *= invn;

  // ---- gate pass 0 (bits 9,8,7 = qubits 0,1,2) fused with load ----
  apply3U(xv, g4, 0);
  wr8<7>(buf, st, xv);
  __syncthreads();
  // ---- gate pass 1 (qubits 3,4,5) ----
  { const int a0 = swz(baseS<4>(t)); rd8<4>(buf, a0, xv); apply3U(xv, g4, 3); wr8<4>(buf, a0, xv); }
  __syncthreads();
  // ---- gate pass 2 (qubits 6,7,8) ----
  { const int a0 = swz(baseS<1>(t)); rd8<1>(buf, a0, xv); apply3U(xv, g4, 6); wr8<1>(buf, a0, xv); }
  __syncthreads();
  // ---- gate pass 3 (qubit 9, bit 0) ----
  { const int a0 = swz(t << 3);
    rd8<0>(buf, a0, xv);
    const float4 A9 = g4[18], B9 = g4[19];
    applyU(A9,B9,xv[0],xv[1]); applyU(A9,B9,xv[2],xv[3]);
    applyU(A9,B9,xv[4],xv[5]); applyU(A9,B9,xv[6],xv[7]);
    wr8<0>(buf, a0, xv);
  }
  __syncthreads();

  // ---- CNOT-ring gather + RY qubits 0,1,2 (bits 9,8,7) ----
  { const int pt = swz(cnot_perm(t));
    #pragma unroll
    for (int m = 0; m < 8; ++m){
      const float2 r = buf[pt ^ swz(cnot_perm(m << 7))];
      xv[m].r = r.x; xv[m].i = r.y;
    }
    __syncthreads();            // all gather reads done before overwrite
    apply3RY(xv, gr, 0);
    wr8<7>(buf, st, xv);
  }
  __syncthreads();
  // ---- RY qubits 3,4,5 ----
  { const int a0 = swz(baseS<4>(t)); rd8<4>(buf, a0, xv); apply3RY(xv, gr, 3); wr8<4>(buf, a0, xv); }
  __syncthreads();
  // ---- RY qubits 6,7,8 ----
  { const int a0 = swz(baseS<1>(t)); rd8<1>(buf, a0, xv); apply3RY(xv, gr, 6); wr8<1>(buf, a0, xv); }
  __syncthreads();
  // ---- RY qubit 9 ----
  { const int a0 = swz(t << 3);
    rd8<0>(buf, a0, xv);
    const float c9 = gr[18], s9 = gr[19];
    applyRY(c9,s9,xv[0],xv[1]); applyRY(c9,s9,xv[2],xv[3]);
    applyRY(c9,s9,xv[4],xv[5]); applyRY(c9,s9,xv[6],xv[7]);
    wr8<0>(buf, a0, xv);
  }
  __syncthreads();

  const float c45 = 0.70710678118f;
  // ---- FFT pass 0: stages span 512,256,128 ----
  { rd8<7>(buf, st, xv);
    float sa, ca; __sincosf((float)t * 6.13592315154256e-3f, &sa, &ca);   // T(t)
    const C tA  = {ca, sa};
    const C tAE = {c45*(ca - sa), c45*(ca + sa)};
    const C tB  = {ca*ca - sa*sa, 2.f*ca*sa};
    const C tC  = {tB.r*tB.r - tB.i*tB.i, 2.f*tB.r*tB.i};
    fft8_stages(xv, tA, tAE, tB, tC);
    wr8<7>(buf, st, xv);
  }
  __syncthreads();
  // ---- FFT pass 1: spans 64,32,16 ----
  { const int a0 = swz(baseS<4>(t)); rd8<4>(buf, a0, xv);
    const int l = t & 15;
    float sa, ca; __sincosf((float)l * 4.90873852123e-2f, &sa, &ca);      // T(8l)
    const C tA  = {ca, sa};
    const C tAE = {c45*(ca - sa), c45*(ca + sa)};
    const C tB  = {ca*ca - sa*sa, 2.f*ca*sa};
    const C tC  = {tB.r*tB.r - tB.i*tB.i, 2.f*tB.r*tB.i};
    fft8_stages(xv, tA, tAE, tB, tC);
    wr8<4>(buf, a0, xv);
  }
  __syncthreads();
  // ---- FFT pass 2: spans 8,4,2 (twiddles are constant selects) ----
  { const int a0 = swz(baseS<1>(t)); rd8<1>(buf, a0, xv);
    const float c22 = 0.92387953251f, s22 = 0.38268343236f;
    const bool l = (t & 1);
    const C tA  = { l ? c22 : 1.f, l ? s22 : 0.f };                       // T(64 l)
    const C tAE = { l ? s22 : c45, l ? c22 : c45 };                       // T(64 l + 128)
    const C tB  = { l ? c45 : 1.f, l ? c45 : 0.f };                       // T(128 l)
    const C tC  = { l ? 0.f : 1.f, l ? 1.f : 0.f };                       // T(256 l)
    fft8_stages(xv, tA, tAE, tB, tC);
    wr8<1>(buf, a0, xv);
  }
  __syncthreads();

  float xr[10], xi[10];
  float S, zz0, zz1, zz2;
  // ---- FFT pass 3 (span 1, tw=1) fused with qubit 0,1,2 expectations ----
  { const int a0 = swz(t << 3);
    rd8<0>(buf, a0, xv);
    #pragma unroll
    for (int m = 0; m < 8; m += 2){
      const C u = {xv[m].r + xv[m+1].r, xv[m].i + xv[m+1].i};
      const C v = {xv[m].r - xv[m+1].r, xv[m].i - xv[m+1].i};
      xv[m] = u; xv[m+1] = v;
    }
    wr8<0>(buf, a0, xv);
    float n[8];
    #pragma unroll
    for (int m = 0; m < 8; ++m) n[m] = xv[m].r*xv[m].r + xv[m].i*xv[m].i;
    S   = n[0]+n[1]+n[2]+n[3]+n[4]+n[5]+n[6]+n[7];
    zz0 = (n[0]+n[2]+n[4]+n[6]) - (n[1]+n[3]+n[5]+n[7]);
    zz1 = (n[0]+n[1]+n[4]+n[5]) - (n[2]+n[3]+n[6]+n[7]);
    zz2 = (n[0]+n[1]+n[2]+n[3]) - (n[4]+n[5]+n[6]+n[7]);
    pairsum<1>(xv, xr[0], xi[0]);
    pairsum<2>(xv, xr[1], xi[1]);
    pairsum<4>(xv, xr[2], xi[2]);
  }
  __syncthreads();

  // ---- expectation read passes (read-only) ----
  { const int a0 = swz(baseS<3>(t)); rd8<3>(buf, a0, xv);
    pairsum<1>(xv, xr[3], xi[3]); pairsum<2>(xv, xr[4], xi[4]); pairsum<4>(xv, xr[5], xi[5]); }
  { const int a0 = swz(baseS<6>(t)); rd8<6>(buf, a0, xv);
    pairsum<1>(xv, xr[6], xi[6]); pairsum<2>(xv, xr[7], xi[7]); pairsum<4>(xv, xr[8], xi[8]); }
  { float r9 = 0.f, i9 = 0.f;
    #pragma unroll
    for (int u = 0; u < 4; ++u){
      const float2 a = buf[st ^ swz(u << 7)];
      const float2 c = buf[st ^ swz(u << 7) ^ swz(512)];
      r9 += a.x*c.x + a.y*c.y;
      i9 += a.x*c.y - a.y*c.x;
    }
    xr[9] = r9; xi[9] = i9;
  }
  __syncthreads();   // all state reads done; buf becomes reduction rows

  // ---- in-register Walsh-Hadamard on S -> Z_3..Z_9 signs over t bits ----
  { float s = S, d0,d1,d2,d3,d4,d5, wv;
    wv = __shfl_xor(s, 1);  d0 = (lane & 1)  ? (wv - s) : (s - wv); s += wv;
    wv = __shfl_xor(s, 2);  d1 = (lane & 2)  ? (wv - s) : (s - wv); s += wv;
    wv = __shfl_xor(s, 4);  d2 = (lane & 4)  ? (wv - s) : (s - wv); s += wv;
    wv = __shfl_xor(s, 8);  d3 = (lane & 8)  ? (wv - s) : (s - wv); s += wv;
    wv = __shfl_xor(s, 16); d4 = (lane & 16) ? (wv - s) : (s - wv); s += wv;
    wv = __shfl_xor(s, 32); d5 = (lane & 32) ? (wv - s) : (s - wv); s += wv;
    d0 += __shfl_xor(d0, 2); d0 += __shfl_xor(d0, 4); d0 += __shfl_xor(d0, 8); d0 += __shfl_xor(d0, 16); d0 += __shfl_xor(d0, 32);
    d1 += __shfl_xor(d1, 4); d1 += __shfl_xor(d1, 8); d1 += __shfl_xor(d1, 16); d1 += __shfl_xor(d1, 32);
    d2 += __shfl_xor(d2, 8); d2 += __shfl_xor(d2, 16); d2 += __shfl_xor(d2, 32);
    d3 += __shfl_xor(d3, 16); d3 += __shfl_xor(d3, 32);
    d4 += __shfl_xor(d4, 32);
    if (lane == 0){
      wz[wave][0] = s;
      wz[wave][1] = d0; wz[wave][2] = d1; wz[wave][3] = d2;
      wz[wave][4] = d3; wz[wave][5] = d4; wz[wave][6] = d5;
    }
  }

  // ---- stage 1: pre-reduce (masks 16,32) and write 12x33 rows ----
  #pragma unroll
  for (int q = 0; q < 10; ++q){
    xr[q] += __shfl_xor(xr[q], 16); xr[q] += __shfl_xor(xr[q], 32);
    xi[q] += __shfl_xor(xi[q], 16); xi[q] += __shfl_xor(xi[q], 32);
  }
  zz0 += __shfl_xor(zz0, 16); zz0 += __shfl_xor(zz0, 32);
  zz1 += __shfl_xor(zz1, 16); zz1 += __shfl_xor(zz1, 32);
  zz2 += __shfl_xor(zz2, 16); zz2 += __shfl_xor(zz2, 32);
  if (lane < 16){
    const int col = wave*16 + lane;
    #pragma unroll
    for (int q = 0; q < 10; ++q) buf[q*33 + col] = make_float2(xr[q], xi[q]);
    buf[10*33 + col] = make_float2(zz0, zz1);
    buf[11*33 + col] = make_float2(zz2, 0.f);
  }
  __syncthreads();

  // ---- stage 2 ----
  const float xs = 2.0f/1024.0f, zs = 1.0f/1024.0f;
  float* ob = out + (size_t)b * 30;
  if (t < 96){
    const int r = t >> 3, c = t & 7;
    float2 a0 = buf[r*33 + c],      a1 = buf[r*33 + c + 8];
    float2 a2 = buf[r*33 + c + 16], a3 = buf[r*33 + c + 24];
    float ax = a0.x + a1.x + a2.x + a3.x;
    float ay = a0.y + a1.y + a2.y + a3.y;
    ax += __shfl_xor(ax, 1); ay += __shfl_xor(ay, 1);
    ax += __shfl_xor(ax, 2); ay += __shfl_xor(ay, 2);
    ax += __shfl_xor(ax, 4); ay += __shfl_xor(ay, 4);
    if (c == 0){
      if (r < 10)      { ob[r] = ax*xs; ob[10+r] = ay*xs; }
      else if (r == 10){ ob[20] = ax*zs; ob[21] = ay*zs; }
      else             { ob[22] = ax*zs; }
    }
  }
  if (t >= 120 && t < 127){
    const int k = t - 120;
    if (k < 6) ob[23+k] = (wz[0][1+k] + wz[1][1+k]) * zs;
    else       ob[29]   = (wz[0][0]   - wz[1][0])   * zs;
  }
}

extern "C" void kernel_launch(void* const* d_in, const int* in_sizes, int n_in,
                              void* d_out, int out_size, void* d_ws, size_t ws_size,
                              hipStream_t stream) {
  const float* x = (const float*)d_in[0];
  const float* w = (const float*)d_in[1];
  float* out = (float*)d_out;
  float* gt  = (float*)d_ws;           // 100 floats of gate tables
  const int B = in_sizes[0] / NFEAT;   // 8192
  gate_prep<<<1, 16, 0, stream>>>(w, gt);
  qqk_kernel<<<B, NT, 0, stream>>>(x, gt, out);
}

// Round 4
// 65.338 us; speedup vs baseline: 1.5839x; 1.5839x over previous
//
#include <hip/hip_runtime.h>
#include <math.h>

#define NFEAT 768
#define NT    128

struct C { float r, i; };

// GF2-linear LDS swizzle (bijective; verified rank-4 bank spread for all patterns)
__device__ __forceinline__ int swz(int j){ return j ^ (j >> 4) ^ ((j >> 2) & 0xC); }

// Composite of the CNOT ring CNOT(0,1),...,CNOT(9,0): s_after[j] = s_before[perm(j)].
// XOR-linear: perm(a^b) = perm(a)^perm(b).
__device__ __forceinline__ int cnot_perm(int j){
  int i = j;
  i ^= ((i >> 0) & 1) << 9;
  i ^= ((i >> 1) & 1) << 0;
  i ^= ((i >> 2) & 1) << 1;
  i ^= ((i >> 3) & 1) << 2;
  i ^= ((i >> 4) & 1) << 3;
  i ^= ((i >> 5) & 1) << 4;
  i ^= ((i >> 6) & 1) << 5;
  i ^= ((i >> 7) & 1) << 6;
  i ^= ((i >> 8) & 1) << 7;
  i ^= ((i >> 9) & 1) << 8;
  return i;
}

__device__ __forceinline__ void applyU(const float4 A, const float4 B, C& a, C& b){
  const float ar=a.r, ai=a.i, br=b.r, bi=b.i;
  a.r = A.x*ar - A.y*ai + A.z*br - A.w*bi;
  a.i = A.x*ai + A.y*ar + A.z*bi + A.w*br;
  b.r = B.x*ar - B.y*ai + B.z*br - B.w*bi;
  b.i = B.x*ai + B.y*ar + B.z*bi + B.w*br;
}

__device__ __forceinline__ void applyRY(float c, float s, C& a, C& b){
  const float ar=a.r, ai=a.i, br=b.r, bi=b.i;
  a.r = c*ar - s*br; a.i = c*ai - s*bi;
  b.r = s*ar + c*br; b.i = s*ai + c*bi;
}

// DIF butterfly, positive exponent: a' = a+b ; b' = (a-b)*tw
__device__ __forceinline__ void bfly(C& a, C& b, const C tw){
  const C u = {a.r + b.r, a.i + b.i};
  const C v = {a.r - b.r, a.i - b.i};
  a = u;
  b.r = v.r*tw.r - v.i*tw.i;
  b.i = v.r*tw.i + v.i*tw.r;
}

template<int S>
__device__ __forceinline__ int baseS(int t){ return (t & ((1<<S)-1)) | ((t >> S) << (S+3)); }

template<int S>
__device__ __forceinline__ void rd8(const float2* buf, int a0, C* xv){
  #pragma unroll
  for (int m = 0; m < 8; ++m){
    const float2 r = buf[a0 ^ swz(m << S)];
    xv[m].r = r.x; xv[m].i = r.y;
  }
}
template<int S>
__device__ __forceinline__ void wr8(float2* buf, int a0, const C* xv){
  #pragma unroll
  for (int m = 0; m < 8; ++m)
    buf[a0 ^ swz(m << S)] = make_float2(xv[m].r, xv[m].i);
}

// three single-qubit gates on bits (P,P-1,P-2) <-> (m+4, m+2, m+1) pairs
__device__ __forceinline__ void apply3U(C* xv, const float4* g4, int Q){
  const float4 A0=g4[2*Q+0], B0=g4[2*Q+1];
  applyU(A0,B0,xv[0],xv[4]); applyU(A0,B0,xv[1],xv[5]); applyU(A0,B0,xv[2],xv[6]); applyU(A0,B0,xv[3],xv[7]);
  const float4 A1=g4[2*Q+2], B1=g4[2*Q+3];
  applyU(A1,B1,xv[0],xv[2]); applyU(A1,B1,xv[1],xv[3]); applyU(A1,B1,xv[4],xv[6]); applyU(A1,B1,xv[5],xv[7]);
  const float4 A2=g4[2*Q+4], B2=g4[2*Q+5];
  applyU(A2,B2,xv[0],xv[1]); applyU(A2,B2,xv[2],xv[3]); applyU(A2,B2,xv[4],xv[5]); applyU(A2,B2,xv[6],xv[7]);
}

__device__ __forceinline__ void apply3RY(C* xv, const float* gr, int Q){
  const float c0 = gr[2*Q+0], s0 = gr[2*Q+1];
  applyRY(c0,s0,xv[0],xv[4]); applyRY(c0,s0,xv[1],xv[5]); applyRY(c0,s0,xv[2],xv[6]); applyRY(c0,s0,xv[3],xv[7]);
  const float c1 = gr[2*Q+2], s1 = gr[2*Q+3];
  applyRY(c1,s1,xv[0],xv[2]); applyRY(c1,s1,xv[1],xv[3]); applyRY(c1,s1,xv[4],xv[6]); applyRY(c1,s1,xv[5],xv[7]);
  const float c2 = gr[2*Q+4], s2 = gr[2*Q+5];
  applyRY(c2,s2,xv[0],xv[1]); applyRY(c2,s2,xv[2],xv[3]); applyRY(c2,s2,xv[4],xv[5]); applyRY(c2,s2,xv[6],xv[7]);
}

// 3 DIF radix-2 stages on 8 regs; stage1 tw = tA*W(128m), stage2 tB*i^(m&1), stage3 tC
__device__ __forceinline__ void fft8_stages(C* xv, const C tA, const C tAE, const C tB, const C tC){
  const C itA  = {-tA.i,  tA.r};
  const C itAE = {-tAE.i, tAE.r};
  bfly(xv[0], xv[4], tA);  bfly(xv[1], xv[5], tAE);
  bfly(xv[2], xv[6], itA); bfly(xv[3], xv[7], itAE);
  const C itB = {-tB.i, tB.r};
  bfly(xv[0], xv[2], tB);  bfly(xv[1], xv[3], itB);
  bfly(xv[4], xv[6], tB);  bfly(xv[5], xv[7], itB);
  bfly(xv[0], xv[1], tC);  bfly(xv[2], xv[3], tC);
  bfly(xv[4], xv[5], tC);  bfly(xv[6], xv[7], tC);
}

template<int MASK>
__device__ __forceinline__ void pairsum(const C* z, float& xr, float& xi){
  float r = 0.f, ii = 0.f;
  #pragma unroll
  for (int m = 0; m < 8; ++m){
    if ((m & MASK) == 0){
      const C a = z[m], b = z[m | MASK];
      r  += a.r*b.r + a.i*b.i;
      ii += a.r*b.i - a.i*b.r;
    }
  }
  xr = r; xi = ii;
}

__global__ void gate_prep(const float* __restrict__ w, float* __restrict__ gt){
  const int t = threadIdx.x;
  if (t >= 10) return;
  const float ha = 0.5f*w[t*4+0], hb = 0.5f*w[t*4+1];
  const float hg = 0.5f*w[t*4+2], hd = 0.5f*w[t*4+3];
  const float ca = cosf(ha), sa = sinf(ha);
  const float cb = cosf(hb), sb = sinf(hb);
  const float cg = cosf(hg), sg = sinf(hg);
  C rx00={ca,0.f}, rx01={0.f,-sa}, rx10={0.f,-sa}, rx11={ca,0.f};
  C ry00={cb,0.f}, ry01={-sb,0.f}, ry10={sb,0.f},  ry11={cb,0.f};
  C a00 = { ry00.r*rx00.r - ry00.i*rx00.i + ry01.r*rx10.r - ry01.i*rx10.i,
            ry00.r*rx00.i + ry00.i*rx00.r + ry01.r*rx10.i + ry01.i*rx10.r };
  C a01 = { ry00.r*rx01.r - ry00.i*rx01.i + ry01.r*rx11.r - ry01.i*rx11.i,
            ry00.r*rx01.i + ry00.i*rx01.r + ry01.r*rx11.i + ry01.i*rx11.r };
  C a10 = { ry10.r*rx00.r - ry10.i*rx00.i + ry11.r*rx10.r - ry11.i*rx10.i,
            ry10.r*rx00.i + ry10.i*rx00.r + ry11.r*rx10.i + ry11.i*rx10.r };
  C a11 = { ry10.r*rx01.r - ry10.i*rx01.i + ry11.r*rx11.r - ry11.i*rx11.i,
            ry10.r*rx01.i + ry10.i*rx01.r + ry11.r*rx11.i + ry11.i*rx11.r };
  // RZ = diag(cg - i sg, cg + i sg)
  C u00 = { cg*a00.r + sg*a00.i, cg*a00.i - sg*a00.r };
  C u01 = { cg*a01.r + sg*a01.i, cg*a01.i - sg*a01.r };
  C u10 = { cg*a10.r - sg*a10.i, cg*a10.i + sg*a10.r };
  C u11 = { cg*a11.r - sg*a11.i, cg*a11.i + sg*a11.r };
  gt[8*t+0]=u00.r; gt[8*t+1]=u00.i; gt[8*t+2]=u01.r; gt[8*t+3]=u01.i;
  gt[8*t+4]=u10.r; gt[8*t+5]=u10.i; gt[8*t+6]=u11.r; gt[8*t+7]=u11.i;
  gt[80+2*t] = cosf(hd); gt[81+2*t] = sinf(hd);
}

__global__ void __launch_bounds__(NT, 4)   // R3 post-mortem: (NT,8) capped VGPR at 64 -> massive spills
qqk_kernel(const float* __restrict__ x, const float* __restrict__ gt,
           float* __restrict__ out)
{
  __shared__ float2 buf[1024];   // swizzled state; later aliased as 12x33 float2 rows
  __shared__ float  wred[2];
  __shared__ float  wz[2][7];    // per-wave WH partials (total, d0..d5)

  const int b    = blockIdx.x;
  const int t    = threadIdx.x;
  const int wave = t >> 6;
  const int lane = t & 63;
  const float4* g4 = (const float4*)gt;
  const float*  gr = gt + 80;
  const int st = swz(t);

  // ---- global load (6 cols + 2 zero pads) + norm ----
  C xv[8];
  const float* xb = x + (size_t)b * NFEAT;
  float ss = 0.f;
  #pragma unroll
  for (int m = 0; m < 6; ++m){ const float v = xb[t + 128*m]; xv[m] = {v, 0.f}; ss += v*v; }
  xv[6] = {0.f,0.f}; xv[7] = {0.f,0.f};
  #pragma unroll
  for (int m = 1; m < 64; m <<= 1) ss += __shfl_xor(ss, m);
  if (lane == 0) wred[wave] = ss;
  __syncthreads();
  const float invn = 1.0f / fmaxf(sqrtf(wred[0] + wred[1]), 1e-8f);
  #pragma unroll
  for (int m = 0; m < 6; ++m) xv[m].r *= invn;

  // ---- gate pass 0 (bits 9,8,7 = qubits 0,1,2) fused with load ----
  apply3U(xv, g4, 0);
  wr8<7>(buf, st, xv);
  __syncthreads();
  // ---- gate pass 1 (qubits 3,4,5) ----
  { const int a0 = swz(baseS<4>(t)); rd8<4>(buf, a0, xv); apply3U(xv, g4, 3); wr8<4>(buf, a0, xv); }
  __syncthreads();
  // ---- gate pass 2 (qubits 6,7,8) ----
  { const int a0 = swz(baseS<1>(t)); rd8<1>(buf, a0, xv); apply3U(xv, g4, 6); wr8<1>(buf, a0, xv); }
  __syncthreads();
  // ---- gate pass 3 (qubit 9, bit 0) ----
  { const int a0 = swz(t << 3);
    rd8<0>(buf, a0, xv);
    const float4 A9 = g4[18], B9 = g4[19];
    applyU(A9,B9,xv[0],xv[1]); applyU(A9,B9,xv[2],xv[3]);
    applyU(A9,B9,xv[4],xv[5]); applyU(A9,B9,xv[6],xv[7]);
    wr8<0>(buf, a0, xv);
  }
  __syncthreads();

  // ---- CNOT-ring gather + RY qubits 0,1,2 (bits 9,8,7) ----
  { const int pt = swz(cnot_perm(t));
    #pragma unroll
    for (int m = 0; m < 8; ++m){
      const float2 r = buf[pt ^ swz(cnot_perm(m << 7))];
      xv[m].r = r.x; xv[m].i = r.y;
    }
    __syncthreads();            // all gather reads done before overwrite
    apply3RY(xv, gr, 0);
    wr8<7>(buf, st, xv);
  }
  __syncthreads();
  // ---- RY qubits 3,4,5 ----
  { const int a0 = swz(baseS<4>(t)); rd8<4>(buf, a0, xv); apply3RY(xv, gr, 3); wr8<4>(buf, a0, xv); }
  __syncthreads();
  // ---- RY qubits 6,7,8 ----
  { const int a0 = swz(baseS<1>(t)); rd8<1>(buf, a0, xv); apply3RY(xv, gr, 6); wr8<1>(buf, a0, xv); }
  __syncthreads();
  // ---- RY qubit 9 ----
  { const int a0 = swz(t << 3);
    rd8<0>(buf, a0, xv);
    const float c9 = gr[18], s9 = gr[19];
    applyRY(c9,s9,xv[0],xv[1]); applyRY(c9,s9,xv[2],xv[3]);
    applyRY(c9,s9,xv[4],xv[5]); applyRY(c9,s9,xv[6],xv[7]);
    wr8<0>(buf, a0, xv);
  }
  __syncthreads();

  const float c45 = 0.70710678118f;
  // ---- FFT pass 0: stages span 512,256,128 ----
  { rd8<7>(buf, st, xv);
    float sa, ca; __sincosf((float)t * 6.13592315154256e-3f, &sa, &ca);   // T(t)
    const C tA  = {ca, sa};
    const C tAE = {c45*(ca - sa), c45*(ca + sa)};
    const C tB  = {ca*ca - sa*sa, 2.f*ca*sa};
    const C tC  = {tB.r*tB.r - tB.i*tB.i, 2.f*tB.r*tB.i};
    fft8_stages(xv, tA, tAE, tB, tC);
    wr8<7>(buf, st, xv);
  }
  __syncthreads();
  // ---- FFT pass 1: spans 64,32,16 ----
  { const int a0 = swz(baseS<4>(t)); rd8<4>(buf, a0, xv);
    const int l = t & 15;
    float sa, ca; __sincosf((float)l * 4.90873852123e-2f, &sa, &ca);      // T(8l)
    const C tA  = {ca, sa};
    const C tAE = {c45*(ca - sa), c45*(ca + sa)};
    const C tB  = {ca*ca - sa*sa, 2.f*ca*sa};
    const C tC  = {tB.r*tB.r - tB.i*tB.i, 2.f*tB.r*tB.i};
    fft8_stages(xv, tA, tAE, tB, tC);
    wr8<4>(buf, a0, xv);
  }
  __syncthreads();
  // ---- FFT pass 2: spans 8,4,2 (twiddles are constant selects) ----
  { const int a0 = swz(baseS<1>(t)); rd8<1>(buf, a0, xv);
    const float c22 = 0.92387953251f, s22 = 0.38268343236f;
    const bool l = (t & 1);
    const C tA  = { l ? c22 : 1.f, l ? s22 : 0.f };                       // T(64 l)
    const C tAE = { l ? s22 : c45, l ? c22 : c45 };                       // T(64 l + 128)
    const C tB  = { l ? c45 : 1.f, l ? c45 : 0.f };                       // T(128 l)
    const C tC  = { l ? 0.f : 1.f, l ? 1.f : 0.f };                       // T(256 l)
    fft8_stages(xv, tA, tAE, tB, tC);
    wr8<1>(buf, a0, xv);
  }
  __syncthreads();

  float xr[10], xi[10];
  float S, zz0, zz1, zz2;
  // ---- FFT pass 3 (span 1, tw=1) fused with qubit 0,1,2 expectations ----
  { const int a0 = swz(t << 3);
    rd8<0>(buf, a0, xv);
    #pragma unroll
    for (int m = 0; m < 8; m += 2){
      const C u = {xv[m].r + xv[m+1].r, xv[m].i + xv[m+1].i};
      const C v = {xv[m].r - xv[m+1].r, xv[m].i - xv[m+1].i};
      xv[m] = u; xv[m+1] = v;
    }
    wr8<0>(buf, a0, xv);
    float n[8];
    #pragma unroll
    for (int m = 0; m < 8; ++m) n[m] = xv[m].r*xv[m].r + xv[m].i*xv[m].i;
    S   = n[0]+n[1]+n[2]+n[3]+n[4]+n[5]+n[6]+n[7];
    zz0 = (n[0]+n[2]+n[4]+n[6]) - (n[1]+n[3]+n[5]+n[7]);
    zz1 = (n[0]+n[1]+n[4]+n[5]) - (n[2]+n[3]+n[6]+n[7]);
    zz2 = (n[0]+n[1]+n[2]+n[3]) - (n[4]+n[5]+n[6]+n[7]);
    pairsum<1>(xv, xr[0], xi[0]);
    pairsum<2>(xv, xr[1], xi[1]);
    pairsum<4>(xv, xr[2], xi[2]);
  }
  __syncthreads();

  // ---- expectation read passes (read-only) ----
  { const int a0 = swz(baseS<3>(t)); rd8<3>(buf, a0, xv);
    pairsum<1>(xv, xr[3], xi[3]); pairsum<2>(xv, xr[4], xi[4]); pairsum<4>(xv, xr[5], xi[5]); }
  { const int a0 = swz(baseS<6>(t)); rd8<6>(buf, a0, xv);
    pairsum<1>(xv, xr[6], xi[6]); pairsum<2>(xv, xr[7], xi[7]); pairsum<4>(xv, xr[8], xi[8]); }
  { float r9 = 0.f, i9 = 0.f;
    #pragma unroll
    for (int u = 0; u < 4; ++u){
      const float2 a = buf[st ^ swz(u << 7)];
      const float2 c = buf[st ^ swz(u << 7) ^ swz(512)];
      r9 += a.x*c.x + a.y*c.y;
      i9 += a.x*c.y - a.y*c.x;
    }
    xr[9] = r9; xi[9] = i9;
  }
  __syncthreads();   // all state reads done; buf becomes reduction rows

  // ---- in-register Walsh-Hadamard on S -> Z_3..Z_9 signs over t bits ----
  { float s = S, d0,d1,d2,d3,d4,d5, wv;
    wv = __shfl_xor(s, 1);  d0 = (lane & 1)  ? (wv - s) : (s - wv); s += wv;
    wv = __shfl_xor(s, 2);  d1 = (lane & 2)  ? (wv - s) : (s - wv); s += wv;
    wv = __shfl_xor(s, 4);  d2 = (lane & 4)  ? (wv - s) : (s - wv); s += wv;
    wv = __shfl_xor(s, 8);  d3 = (lane & 8)  ? (wv - s) : (s - wv); s += wv;
    wv = __shfl_xor(s, 16); d4 = (lane & 16) ? (wv - s) : (s - wv); s += wv;
    wv = __shfl_xor(s, 32); d5 = (lane & 32) ? (wv - s) : (s - wv); s += wv;
    d0 += __shfl_xor(d0, 2); d0 += __shfl_xor(d0, 4); d0 += __shfl_xor(d0, 8); d0 += __shfl_xor(d0, 16); d0 += __shfl_xor(d0, 32);
    d1 += __shfl_xor(d1, 4); d1 += __shfl_xor(d1, 8); d1 += __shfl_xor(d1, 16); d1 += __shfl_xor(d1, 32);
    d2 += __shfl_xor(d2, 8); d2 += __shfl_xor(d2, 16); d2 += __shfl_xor(d2, 32);
    d3 += __shfl_xor(d3, 16); d3 += __shfl_xor(d3, 32);
    d4 += __shfl_xor(d4, 32);
    if (lane == 0){
      wz[wave][0] = s;
      wz[wave][1] = d0; wz[wave][2] = d1; wz[wave][3] = d2;
      wz[wave][4] = d3; wz[wave][5] = d4; wz[wave][6] = d5;
    }
  }

  // ---- stage 1: pre-reduce (masks 16,32) and write 12x33 rows ----
  #pragma unroll
  for (int q = 0; q < 10; ++q){
    xr[q] += __shfl_xor(xr[q], 16); xr[q] += __shfl_xor(xr[q], 32);
    xi[q] += __shfl_xor(xi[q], 16); xi[q] += __shfl_xor(xi[q], 32);
  }
  zz0 += __shfl_xor(zz0, 16); zz0 += __shfl_xor(zz0, 32);
  zz1 += __shfl_xor(zz1, 16); zz1 += __shfl_xor(zz1, 32);
  zz2 += __shfl_xor(zz2, 16); zz2 += __shfl_xor(zz2, 32);
  if (lane < 16){
    const int col = wave*16 + lane;
    #pragma unroll
    for (int q = 0; q < 10; ++q) buf[q*33 + col] = make_float2(xr[q], xi[q]);
    buf[10*33 + col] = make_float2(zz0, zz1);
    buf[11*33 + col] = make_float2(zz2, 0.f);
  }
  __syncthreads();

  // ---- stage 2 ----
  const float xs = 2.0f/1024.0f, zs = 1.0f/1024.0f;
  float* ob = out + (size_t)b * 30;
  if (t < 96){
    const int r = t >> 3, c = t & 7;
    float2 a0 = buf[r*33 + c],      a1 = buf[r*33 + c + 8];
    float2 a2 = buf[r*33 + c + 16], a3 = buf[r*33 + c + 24];
    float ax = a0.x + a1.x + a2.x + a3.x;
    float ay = a0.y + a1.y + a2.y + a3.y;
    ax += __shfl_xor(ax, 1); ay += __shfl_xor(ay, 1);
    ax += __shfl_xor(ax, 2); ay += __shfl_xor(ay, 2);
    ax += __shfl_xor(ax, 4); ay += __shfl_xor(ay, 4);
    if (c == 0){
      if (r < 10)      { ob[r] = ax*xs; ob[10+r] = ay*xs; }
      else if (r == 10){ ob[20] = ax*zs; ob[21] = ay*zs; }
      else             { ob[22] = ax*zs; }
    }
  }
  if (t >= 120 && t < 127){
    const int k = t - 120;
    if (k < 6) ob[23+k] = (wz[0][1+k] + wz[1][1+k]) * zs;
    else       ob[29]   = (wz[0][0]   - wz[1][0])   * zs;
  }
}

extern "C" void kernel_launch(void* const* d_in, const int* in_sizes, int n_in,
                              void* d_out, int out_size, void* d_ws, size_t ws_size,
                              hipStream_t stream) {
  const float* x = (const float*)d_in[0];
  const float* w = (const float*)d_in[1];
  float* out = (float*)d_out;
  float* gt  = (float*)d_ws;           // 100 floats of gate tables
  const int B = in_sizes[0] / NFEAT;   // 8192
  gate_prep<<<1, 16, 0, stream>>>(w, gt);
  qqk_kernel<<<B, NT, 0, stream>>>(x, gt, out);
}

// Round 5
// 62.847 us; speedup vs baseline: 1.6467x; 1.0396x over previous
//
#include <hip/hip_runtime.h>
#include <math.h>

#define NFEAT 768
#define NT    256   // two independent 128-thread halves, one batch element each

typedef float f2 __attribute__((ext_vector_type(2)));

// GF2-linear LDS swizzle (bijective; verified rank-4 bank spread for all patterns)
__device__ __forceinline__ int swz(int j){ return j ^ (j >> 4) ^ ((j >> 2) & 0xC); }

// Composite of the CNOT ring CNOT(0,1),...,CNOT(9,0): s_after[j] = s_before[perm(j)].
__device__ __forceinline__ int cnot_perm(int j){
  int i = j;
  i ^= ((i >> 0) & 1) << 9;
  i ^= ((i >> 1) & 1) << 0;
  i ^= ((i >> 2) & 1) << 1;
  i ^= ((i >> 3) & 1) << 2;
  i ^= ((i >> 4) & 1) << 3;
  i ^= ((i >> 5) & 1) << 4;
  i ^= ((i >> 6) & 1) << 5;
  i ^= ((i >> 7) & 1) << 6;
  i ^= ((i >> 8) & 1) << 7;
  i ^= ((i >> 9) & 1) << 8;
  return i;
}

// ---- packed-f32 complex primitives (VOP3P) ----
// cmul: d = s (x) v = (s.lo*v.lo - s.hi*v.hi, s.lo*v.hi + s.hi*v.lo)
__device__ __forceinline__ f2 pk_cmul(f2 s, f2 v){
  f2 d;
  asm("v_pk_mul_f32 %0, %1, %2 op_sel:[0,0] op_sel_hi:[0,1]\n\t"
      "v_pk_fma_f32 %0, %1, %2, %0 op_sel:[1,1,0] op_sel_hi:[1,0,1] neg_lo:[0,1,0]"
      : "=&v"(d) : "v"(s), "v"(v));
  return d;
}
// cfma: d = acc + s (x) v
__device__ __forceinline__ f2 pk_cfma(f2 s, f2 v, f2 acc){
  f2 d;
  asm("v_pk_fma_f32 %0, %2, %3, %1 op_sel:[0,0,0] op_sel_hi:[0,1,1]\n\t"
      "v_pk_fma_f32 %0, %2, %3, %0 op_sel:[1,1,0] op_sel_hi:[1,0,1] neg_lo:[0,1,0]"
      : "=&v"(d) : "v"(acc), "v"(s), "v"(v));
  return d;
}
// cross: d = acc + (a.r*b.i, -a.i*b.r)   (for Im<conj(a) b> pair accumulation)
__device__ __forceinline__ f2 pk_cross(f2 a, f2 b, f2 acc){
  f2 d;
  asm("v_pk_fma_f32 %0, %2, %3, %1 op_sel:[0,1,0] op_sel_hi:[1,0,1] neg_hi:[1,0,0]"
      : "=&v"(d) : "v"(acc), "v"(a), "v"(b));
  return d;
}
// RY with cs=(c,s): a' = c*a - s*b ; b' = s*a + c*b (componentwise pairs)
__device__ __forceinline__ void pk_ry(f2 cs, f2& a, f2& b){
  f2 t1, t2, na, nb;
  asm("v_pk_mul_f32 %0, %2, %3 op_sel:[1,0] op_sel_hi:[1,1] neg_lo:[1,0] neg_hi:[1,0]\n\t"
      "v_pk_mul_f32 %1, %2, %4 op_sel:[1,0] op_sel_hi:[1,1]"
      : "=&v"(t1), "=&v"(t2) : "v"(cs), "v"(b), "v"(a));
  asm("v_pk_fma_f32 %0, %2, %3, %4 op_sel:[0,0,0] op_sel_hi:[0,1,1]\n\t"
      "v_pk_fma_f32 %1, %2, %5, %6 op_sel:[0,0,0] op_sel_hi:[0,1,1]"
      : "=&v"(na), "=&v"(nb) : "v"(cs), "v"(a), "v"(t1), "v"(b), "v"(t2));
  a = na; b = nb;
}
// full 2x2 complex gate
__device__ __forceinline__ void pk_u(f2 u00, f2 u01, f2 u10, f2 u11, f2& a, f2& b){
  const f2 na = pk_cfma(u01, b, pk_cmul(u00, a));
  const f2 nb = pk_cfma(u11, b, pk_cmul(u10, a));
  a = na; b = nb;
}
// DIF butterfly, positive exponent: a' = a+b ; b' = (a-b)*tw
__device__ __forceinline__ void bfly(f2& a, f2& b, f2 tw){
  const f2 u = a + b;
  const f2 v = a - b;
  a = u;
  b = pk_cmul(tw, v);
}

template<int S>
__device__ __forceinline__ int baseS(int t){ return (t & ((1<<S)-1)) | ((t >> S) << (S+3)); }

template<int S>
__device__ __forceinline__ void rd8(const f2* bb, int a0, f2* xv){
  #pragma unroll
  for (int m = 0; m < 8; ++m) xv[m] = bb[a0 ^ swz(m << S)];
}
template<int S>
__device__ __forceinline__ void wr8(f2* bb, int a0, const f2* xv){
  #pragma unroll
  for (int m = 0; m < 8; ++m) bb[a0 ^ swz(m << S)] = xv[m];
}

// three 2x2 gates on the (m+4, m+2, m+1) pair axes
__device__ __forceinline__ void apply3U(f2* xv, const f2* g2, int Q){
  { const f2 u00=g2[4*Q+0], u01=g2[4*Q+1], u10=g2[4*Q+2], u11=g2[4*Q+3];
    pk_u(u00,u01,u10,u11,xv[0],xv[4]); pk_u(u00,u01,u10,u11,xv[1],xv[5]);
    pk_u(u00,u01,u10,u11,xv[2],xv[6]); pk_u(u00,u01,u10,u11,xv[3],xv[7]); }
  { const f2 u00=g2[4*Q+4], u01=g2[4*Q+5], u10=g2[4*Q+6], u11=g2[4*Q+7];
    pk_u(u00,u01,u10,u11,xv[0],xv[2]); pk_u(u00,u01,u10,u11,xv[1],xv[3]);
    pk_u(u00,u01,u10,u11,xv[4],xv[6]); pk_u(u00,u01,u10,u11,xv[5],xv[7]); }
  { const f2 u00=g2[4*Q+8], u01=g2[4*Q+9], u10=g2[4*Q+10], u11=g2[4*Q+11];
    pk_u(u00,u01,u10,u11,xv[0],xv[1]); pk_u(u00,u01,u10,u11,xv[2],xv[3]);
    pk_u(u00,u01,u10,u11,xv[4],xv[5]); pk_u(u00,u01,u10,u11,xv[6],xv[7]); }
}

__device__ __forceinline__ void apply3RY(f2* xv, const f2* gry, int Q){
  { const f2 cs = gry[Q];
    pk_ry(cs,xv[0],xv[4]); pk_ry(cs,xv[1],xv[5]); pk_ry(cs,xv[2],xv[6]); pk_ry(cs,xv[3],xv[7]); }
  { const f2 cs = gry[Q+1];
    pk_ry(cs,xv[0],xv[2]); pk_ry(cs,xv[1],xv[3]); pk_ry(cs,xv[4],xv[6]); pk_ry(cs,xv[5],xv[7]); }
  { const f2 cs = gry[Q+2];
    pk_ry(cs,xv[0],xv[1]); pk_ry(cs,xv[2],xv[3]); pk_ry(cs,xv[4],xv[5]); pk_ry(cs,xv[6],xv[7]); }
}

// 3 DIF radix-2 stages on 8 regs
__device__ __forceinline__ void fft8_stages(f2* xv, const f2 tA, const f2 tAE, const f2 tB, const f2 tC){
  const f2 itA  = {-tA.y,  tA.x};
  const f2 itAE = {-tAE.y, tAE.x};
  bfly(xv[0], xv[4], tA);  bfly(xv[1], xv[5], tAE);
  bfly(xv[2], xv[6], itA); bfly(xv[3], xv[7], itAE);
  const f2 itB = {-tB.y, tB.x};
  bfly(xv[0], xv[2], tB);  bfly(xv[1], xv[3], itB);
  bfly(xv[4], xv[6], tB);  bfly(xv[5], xv[7], itB);
  bfly(xv[0], xv[1], tC);  bfly(xv[2], xv[3], tC);
  bfly(xv[4], xv[5], tC);  bfly(xv[6], xv[7], tC);
}

template<int MASK>
__device__ __forceinline__ void pairsum(const f2* z, float& xr, float& xi){
  f2 rp = {0.f, 0.f}, ip = {0.f, 0.f};
  #pragma unroll
  for (int m = 0; m < 8; ++m){
    if ((m & MASK) == 0){
      rp = z[m]*z[m|MASK] + rp;            // (ar*br, ai*bi) accumulate
      ip = pk_cross(z[m], z[m|MASK], ip);  // (ar*bi, -ai*br) accumulate
    }
  }
  xr = rp.x + rp.y; xi = ip.x + ip.y;
}

__global__ void gate_prep(const float* __restrict__ w, float* __restrict__ gt){
  const int t = threadIdx.x;
  if (t >= 10) return;
  const float ha = 0.5f*w[t*4+0], hb = 0.5f*w[t*4+1];
  const float hg = 0.5f*w[t*4+2], hd = 0.5f*w[t*4+3];
  const float ca = cosf(ha), sa = sinf(ha);
  const float cb = cosf(hb), sb = sinf(hb);
  const float cg = cosf(hg), sg = sinf(hg);
  // M = RY*RX (RX off-diagonals are -i*sa)
  const float m00r = cb*ca, m00i =  sb*sa;
  const float m01r = -sb*ca, m01i = -cb*sa;
  const float m10r =  sb*ca, m10i = -cb*sa;
  const float m11r = cb*ca,  m11i = -sb*sa;
  // U = RZ*M, RZ = diag(cg - i sg, cg + i sg)
  gt[8*t+0] = cg*m00r + sg*m00i;  gt[8*t+1] = cg*m00i - sg*m00r;
  gt[8*t+2] = cg*m01r + sg*m01i;  gt[8*t+3] = cg*m01i - sg*m01r;
  gt[8*t+4] = cg*m10r - sg*m10i;  gt[8*t+5] = cg*m10i + sg*m10r;
  gt[8*t+6] = cg*m11r - sg*m11i;  gt[8*t+7] = cg*m11i + sg*m11r;
  gt[80+2*t] = cosf(hd); gt[81+2*t] = sinf(hd);
}

__global__ void __launch_bounds__(NT, 4)
qqk_kernel(const float* __restrict__ x, const float* __restrict__ gt,
           float* __restrict__ out)
{
  __shared__ f2    buf[2][1024];   // per-half swizzled state; later aliased as 12x33 rows
  __shared__ float wred[2][2];
  __shared__ float wz[2][2][7];    // per-half per-wave WH partials

  const int b    = blockIdx.x;
  const int t    = threadIdx.x;
  const int half = t >> 7;
  const int tl   = t & 127;
  const int hw   = (t >> 6) & 1;   // wave within half
  const int lane = t & 63;
  const f2* g2  = (const f2*)gt;
  const f2* gry = (const f2*)(gt + 80);
  f2* bb = buf[half];
  const int st = swz(tl);

  // ---- global load (6 cols + 2 zero pads) + norm ----
  f2 xv[8];
  const float* xb = x + (size_t)(2*b + half) * NFEAT;
  float ss = 0.f;
  #pragma unroll
  for (int m = 0; m < 6; ++m){ const float v = xb[tl + 128*m]; xv[m] = f2{v, 0.f}; ss += v*v; }
  xv[6] = f2{0.f,0.f}; xv[7] = f2{0.f,0.f};
  #pragma unroll
  for (int m = 1; m < 64; m <<= 1) ss += __shfl_xor(ss, m);
  if (lane == 0) wred[half][hw] = ss;
  __syncthreads();
  const float invn = 1.0f / fmaxf(sqrtf(wred[half][0] + wred[half][1]), 1e-8f);
  #pragma unroll
  for (int m = 0; m < 6; ++m) xv[m].x *= invn;

  // ---- gate pass 0 (bits 9,8,7 = qubits 0,1,2) fused with load ----
  apply3U(xv, g2, 0);
  wr8<7>(bb, st, xv);
  __syncthreads();
  // ---- gate pass 1 (qubits 3,4,5) ----
  { const int a0 = swz(baseS<4>(tl)); rd8<4>(bb, a0, xv); apply3U(xv, g2, 3); wr8<4>(bb, a0, xv); }
  __syncthreads();
  // ---- gate pass 2 (qubits 6,7,8) ----
  { const int a0 = swz(baseS<1>(tl)); rd8<1>(bb, a0, xv); apply3U(xv, g2, 6); wr8<1>(bb, a0, xv); }
  __syncthreads();
  // ---- gate pass 3 (qubit 9, bit 0) ----
  { const int a0 = swz(tl << 3);
    rd8<0>(bb, a0, xv);
    const f2 u00=g2[36], u01=g2[37], u10=g2[38], u11=g2[39];
    pk_u(u00,u01,u10,u11,xv[0],xv[1]); pk_u(u00,u01,u10,u11,xv[2],xv[3]);
    pk_u(u00,u01,u10,u11,xv[4],xv[5]); pk_u(u00,u01,u10,u11,xv[6],xv[7]);
    wr8<0>(bb, a0, xv);
  }
  __syncthreads();

  // ---- CNOT-ring gather + RY qubits 0,1,2 (bits 9,8,7) ----
  { const int pt = swz(cnot_perm(tl));
    #pragma unroll
    for (int m = 0; m < 8; ++m) xv[m] = bb[pt ^ swz(cnot_perm(m << 7))];
    __syncthreads();            // all gather reads done before overwrite
    apply3RY(xv, gry, 0);
    wr8<7>(bb, st, xv);
  }
  __syncthreads();
  // ---- RY qubits 3,4,5 ----
  { const int a0 = swz(baseS<4>(tl)); rd8<4>(bb, a0, xv); apply3RY(xv, gry, 3); wr8<4>(bb, a0, xv); }
  __syncthreads();
  // ---- RY qubits 6,7,8 ----
  { const int a0 = swz(baseS<1>(tl)); rd8<1>(bb, a0, xv); apply3RY(xv, gry, 6); wr8<1>(bb, a0, xv); }
  __syncthreads();
  // ---- RY qubit 9 ----
  { const int a0 = swz(tl << 3);
    rd8<0>(bb, a0, xv);
    const f2 cs = gry[9];
    pk_ry(cs,xv[0],xv[1]); pk_ry(cs,xv[2],xv[3]); pk_ry(cs,xv[4],xv[5]); pk_ry(cs,xv[6],xv[7]);
    wr8<0>(bb, a0, xv);
  }
  __syncthreads();

  const float c45 = 0.70710678118f;
  // ---- FFT pass 0: stages span 512,256,128 ----
  { rd8<7>(bb, st, xv);
    float sa, ca; __sincosf((float)tl * 6.13592315154256e-3f, &sa, &ca);   // T(tl)
    const f2 tA  = {ca, sa};
    const f2 tAE = {c45*(ca - sa), c45*(ca + sa)};
    const f2 tB  = pk_cmul(tA, tA);
    const f2 tC  = pk_cmul(tB, tB);
    fft8_stages(xv, tA, tAE, tB, tC);
    wr8<7>(bb, st, xv);
  }
  __syncthreads();
  // ---- FFT pass 1: spans 64,32,16 ----
  { const int a0 = swz(baseS<4>(tl)); rd8<4>(bb, a0, xv);
    const int l = tl & 15;
    float sa, ca; __sincosf((float)l * 4.90873852123e-2f, &sa, &ca);       // T(8l)
    const f2 tA  = {ca, sa};
    const f2 tAE = {c45*(ca - sa), c45*(ca + sa)};
    const f2 tB  = pk_cmul(tA, tA);
    const f2 tC  = pk_cmul(tB, tB);
    fft8_stages(xv, tA, tAE, tB, tC);
    wr8<4>(bb, a0, xv);
  }
  __syncthreads();
  // ---- FFT pass 2: spans 8,4,2 (twiddles are constant selects) ----
  { const int a0 = swz(baseS<1>(tl)); rd8<1>(bb, a0, xv);
    const float c22 = 0.92387953251f, s22 = 0.38268343236f;
    const bool l = (tl & 1);
    const f2 tA  = { l ? c22 : 1.f, l ? s22 : 0.f };                       // T(64 l)
    const f2 tAE = { l ? s22 : c45, l ? c22 : c45 };                       // T(64 l + 128)
    const f2 tB  = { l ? c45 : 1.f, l ? c45 : 0.f };                       // T(128 l)
    const f2 tC  = { l ? 0.f : 1.f, l ? 1.f : 0.f };                       // T(256 l)
    fft8_stages(xv, tA, tAE, tB, tC);
    wr8<1>(bb, a0, xv);
  }
  __syncthreads();

  float xr[10], xi[10];
  float S, zz0, zz1, zz2;
  // ---- FFT pass 3 (span 1, tw=1) fused with qubit 0,1,2 expectations ----
  { const int a0 = swz(tl << 3);
    rd8<0>(bb, a0, xv);
    #pragma unroll
    for (int m = 0; m < 8; m += 2){
      const f2 u = xv[m] + xv[m+1];
      const f2 v = xv[m] - xv[m+1];
      xv[m] = u; xv[m+1] = v;
    }
    wr8<0>(bb, a0, xv);
    float n[8];
    #pragma unroll
    for (int m = 0; m < 8; ++m){ const f2 nm = xv[m]*xv[m]; n[m] = nm.x + nm.y; }
    S   = n[0]+n[1]+n[2]+n[3]+n[4]+n[5]+n[6]+n[7];
    zz0 = (n[0]+n[2]+n[4]+n[6]) - (n[1]+n[3]+n[5]+n[7]);
    zz1 = (n[0]+n[1]+n[4]+n[5]) - (n[2]+n[3]+n[6]+n[7]);
    zz2 = (n[0]+n[1]+n[2]+n[3]) - (n[4]+n[5]+n[6]+n[7]);
    pairsum<1>(xv, xr[0], xi[0]);
    pairsum<2>(xv, xr[1], xi[1]);
    pairsum<4>(xv, xr[2], xi[2]);
  }
  __syncthreads();

  // ---- expectation read passes (read-only) ----
  { const int a0 = swz(baseS<3>(tl)); rd8<3>(bb, a0, xv);
    pairsum<1>(xv, xr[3], xi[3]); pairsum<2>(xv, xr[4], xi[4]); pairsum<4>(xv, xr[5], xi[5]); }
  { const int a0 = swz(baseS<6>(tl)); rd8<6>(bb, a0, xv);
    pairsum<1>(xv, xr[6], xi[6]); pairsum<2>(xv, xr[7], xi[7]); pairsum<4>(xv, xr[8], xi[8]); }
  { f2 rp = {0.f,0.f}, ip = {0.f,0.f};
    #pragma unroll
    for (int u = 0; u < 4; ++u){
      const f2 a = bb[st ^ swz(u << 7)];
      const f2 c = bb[st ^ swz(u << 7) ^ swz(512)];
      rp = a*c + rp;
      ip = pk_cross(a, c, ip);
    }
    xr[9] = rp.x + rp.y; xi[9] = ip.x + ip.y;
  }
  __syncthreads();   // all state reads done; buf becomes reduction rows

  // ---- in-register Walsh-Hadamard on S -> Z_3..Z_9 signs over tl bits ----
  { float s = S, d0,d1,d2,d3,d4,d5, wv;
    wv = __shfl_xor(s, 1);  d0 = (lane & 1)  ? (wv - s) : (s - wv); s += wv;
    wv = __shfl_xor(s, 2);  d1 = (lane & 2)  ? (wv - s) : (s - wv); s += wv;
    wv = __shfl_xor(s, 4);  d2 = (lane & 4)  ? (wv - s) : (s - wv); s += wv;
    wv = __shfl_xor(s, 8);  d3 = (lane & 8)  ? (wv - s) : (s - wv); s += wv;
    wv = __shfl_xor(s, 16); d4 = (lane & 16) ? (wv - s) : (s - wv); s += wv;
    wv = __shfl_xor(s, 32); d5 = (lane & 32) ? (wv - s) : (s - wv); s += wv;
    d0 += __shfl_xor(d0, 2); d0 += __shfl_xor(d0, 4); d0 += __shfl_xor(d0, 8); d0 += __shfl_xor(d0, 16); d0 += __shfl_xor(d0, 32);
    d1 += __shfl_xor(d1, 4); d1 += __shfl_xor(d1, 8); d1 += __shfl_xor(d1, 16); d1 += __shfl_xor(d1, 32);
    d2 += __shfl_xor(d2, 8); d2 += __shfl_xor(d2, 16); d2 += __shfl_xor(d2, 32);
    d3 += __shfl_xor(d3, 16); d3 += __shfl_xor(d3, 32);
    d4 += __shfl_xor(d4, 32);
    if (lane == 0){
      wz[half][hw][0] = s;
      wz[half][hw][1] = d0; wz[half][hw][2] = d1; wz[half][hw][3] = d2;
      wz[half][hw][4] = d3; wz[half][hw][5] = d4; wz[half][hw][6] = d5;
    }
  }

  // ---- stage 1: pre-reduce (masks 16,32) and write 12x33 rows ----
  #pragma unroll
  for (int q = 0; q < 10; ++q){
    xr[q] += __shfl_xor(xr[q], 16); xr[q] += __shfl_xor(xr[q], 32);
    xi[q] += __shfl_xor(xi[q], 16); xi[q] += __shfl_xor(xi[q], 32);
  }
  zz0 += __shfl_xor(zz0, 16); zz0 += __shfl_xor(zz0, 32);
  zz1 += __shfl_xor(zz1, 16); zz1 += __shfl_xor(zz1, 32);
  zz2 += __shfl_xor(zz2, 16); zz2 += __shfl_xor(zz2, 32);
  if (lane < 16){
    const int col = hw*16 + lane;
    #pragma unroll
    for (int q = 0; q < 10; ++q) bb[q*33 + col] = f2{xr[q], xi[q]};
    bb[10*33 + col] = f2{zz0, zz1};
    bb[11*33 + col] = f2{zz2, 0.f};
  }
  __syncthreads();

  // ---- stage 2 ----
  const float xs = 2.0f/1024.0f, zs = 1.0f/1024.0f;
  float* ob = out + (size_t)(2*b + half) * 30;
  if (tl < 96){
    const int r = tl >> 3, c = tl & 7;
    const f2 a0 = bb[r*33 + c],      a1 = bb[r*33 + c + 8];
    const f2 a2 = bb[r*33 + c + 16], a3 = bb[r*33 + c + 24];
    float ax = a0.x + a1.x + a2.x + a3.x;
    float ay = a0.y + a1.y + a2.y + a3.y;
    ax += __shfl_xor(ax, 1); ay += __shfl_xor(ay, 1);
    ax += __shfl_xor(ax, 2); ay += __shfl_xor(ay, 2);
    ax += __shfl_xor(ax, 4); ay += __shfl_xor(ay, 4);
    if (c == 0){
      if (r < 10)      { ob[r] = ax*xs; ob[10+r] = ay*xs; }
      else if (r == 10){ ob[20] = ax*zs; ob[21] = ay*zs; }
      else             { ob[22] = ax*zs; }
    }
  }
  if (tl >= 120 && tl < 127){
    const int k = tl - 120;
    if (k < 6) ob[23+k] = (wz[half][0][1+k] + wz[half][1][1+k]) * zs;
    else       ob[29]   = (wz[half][0][0]   - wz[half][1][0])   * zs;
  }
}

extern "C" void kernel_launch(void* const* d_in, const int* in_sizes, int n_in,
                              void* d_out, int out_size, void* d_ws, size_t ws_size,
                              hipStream_t stream) {
  const float* x = (const float*)d_in[0];
  const float* w = (const float*)d_in[1];
  float* out = (float*)d_out;
  float* gt  = (float*)d_ws;           // 100 floats of gate tables
  const int B = in_sizes[0] / NFEAT;   // 8192
  gate_prep<<<1, 16, 0, stream>>>(w, gt);
  qqk_kernel<<<B/2, NT, 0, stream>>>(x, gt, out);
}